// Round 8
// baseline (2296.884 us; speedup 1.0000x reference)
//
#include <hip/hip_runtime.h>
#include <stdint.h>

// LocMatcher: 4-layer post-norm transformer encoder + masked log_softmax head.
// Inputs bf16 (detector tolerates f32 via flag); OUTPUT float32.
// R8: attn longest-first block order (qt reversed: work ∝ len, schedule big
// blocks first), K-fragment register double-buffer (hide L2 latency behind
// MFMA), final_proj whole-block dead early-out. Core attn structure = R7
// (LDS V dbuf, 1 barrier/tile, S^T=K*Q^T, packed-trunc P, ones-MFMA denom).

typedef unsigned short u16;
typedef __attribute__((ext_vector_type(8))) short short8;
typedef __attribute__((ext_vector_type(4))) float f32x4;

constexpr int Bn = 32, Sn = 1024, Dn = 512, Ln = 4;
constexpr int BS = Bn * Sn;

__device__ __forceinline__ float b2f(u16 u) {
    union { uint32_t i; float f; } v; v.i = ((uint32_t)u) << 16; return v.f;
}
__device__ __forceinline__ u16 f2b(float f) {
    union { float f; uint32_t i; } v; v.f = f;
    uint32_t r = v.i + 0x7fffu + ((v.i >> 16) & 1u);
    return (u16)(r >> 16);
}
__device__ __forceinline__ float getf(const void* p, size_t i, int F) {
    return F ? ((const float*)p)[i] : b2f(((const u16*)p)[i]);
}
__device__ __forceinline__ void cp16(void* lds, const void* g) {
    __builtin_amdgcn_global_load_lds(
        (__attribute__((address_space(1))) void*)(uintptr_t)g,
        (__attribute__((address_space(3))) void*)(uint32_t)(uintptr_t)lds,
        16, 0, 0);
}
__device__ __forceinline__ float asf(uint32_t u) {
    union { uint32_t i; float f; } v; v.i = u; return v.f;
}

// ---------------------------------------------------------------------------
__global__ __launch_bounds__(256)
void detect_kernel(const void* loc, int* flag)
{
    __shared__ int cnt;
    if (threadIdx.x == 0) cnt = 0;
    __syncthreads();
    const u16* p = (const u16*)loc;
    int c = 0;
    for (int i = threadIdx.x; i < 2048; i += 256) {
        const float v = b2f(p[i]);
        if (!(fabsf(v) <= 100.0f)) c++;
    }
    atomicAdd(&cnt, c);
    __syncthreads();
    if (threadIdx.x == 0) *flag = (cnt >= 64) ? 1 : 0;
}

// ---------------------------------------------------------------------------
// GEMM (m97 structure), dead 128-row M-blocks skipped.
// ---------------------------------------------------------------------------
__global__ __launch_bounds__(256)
void gemm_bt(const u16* __restrict__ A, const u16* __restrict__ Bt,
             const void* __restrict__ bias, int boff, u16* __restrict__ C,
             int N, int K, int relu, const int* __restrict__ flagp,
             const int* __restrict__ dlen)
{
    __shared__ __align__(16) u16 As[128 * 32];
    __shared__ __align__(16) u16 Bs[128 * 32];
    const int bn0 = blockIdx.x * 128, bm0 = blockIdx.y * 128;
    if ((bm0 & 1023) >= dlen[bm0 >> 10]) return;
    const int F = *flagp;
    const int tid = threadIdx.x;
    const int lane = tid & 63, w = tid >> 6;
    const int wm = w >> 1, wn = w & 1;
    const int quad = lane >> 4, l16 = lane & 15;

    const f32x4 vzero = {0.f, 0.f, 0.f, 0.f};
    f32x4 acc[4][4];
#pragma unroll
    for (int i = 0; i < 4; i++)
#pragma unroll
        for (int j = 0; j < 4; j++) acc[i][j] = vzero;

    const int i0 = tid, i1 = tid + 256;
    const u16* a0 = A + (size_t)(bm0 + (i0 >> 2)) * K + (i0 & 3) * 8;
    const u16* a1 = A + (size_t)(bm0 + (i1 >> 2)) * K + (i1 & 3) * 8;
    const u16* b0 = Bt + (size_t)(bn0 + (i0 >> 2)) * K + (i0 & 3) * 8;
    const u16* b1 = Bt + (size_t)(bn0 + (i1 >> 2)) * K + (i1 & 3) * 8;

    for (int k0 = 0; k0 < K; k0 += 32) {
        cp16(As + i0 * 8, a0 + k0);
        cp16(As + i1 * 8, a1 + k0);
        cp16(Bs + i0 * 8, b0 + k0);
        cp16(Bs + i1 * 8, b1 + k0);
        __syncthreads();
        short8 af[4], bfr[4];
#pragma unroll
        for (int t = 0; t < 4; t++)
            af[t] = *(const short8*)&As[(wm * 64 + t * 16 + l16) * 32 + quad * 8];
#pragma unroll
        for (int t = 0; t < 4; t++)
            bfr[t] = *(const short8*)&Bs[(wn * 64 + t * 16 + l16) * 32 + quad * 8];
#pragma unroll
        for (int tm = 0; tm < 4; tm++)
#pragma unroll
            for (int tn = 0; tn < 4; tn++)
                acc[tm][tn] = __builtin_amdgcn_mfma_f32_16x16x32_bf16(
                    af[tm], bfr[tn], acc[tm][tn], 0, 0, 0);
        __syncthreads();
    }
#pragma unroll
    for (int tm = 0; tm < 4; tm++)
#pragma unroll
        for (int tn = 0; tn < 4; tn++) {
            const int col = bn0 + wn * 64 + tn * 16 + l16;
            const float bv = getf(bias, (size_t)boff + col, F);
#pragma unroll
            for (int r = 0; r < 4; r++) {
                const int row = bm0 + wm * 64 + tm * 16 + quad * 4 + r;
                float v = acc[tm][tn][r] + bv;
                if (relu) v = fmaxf(v, 0.0f);
                C[(size_t)row * N + col] = f2b(v);
            }
        }
}

// ---------------------------------------------------------------------------
// Flash attention v5: 128 q/block, LDS V dbuf (1 barrier/tile), S^T=K*Q^T,
// swizzled packed-trunc P, ones-MFMA denom, K register double-buffer,
// longest-first block order (qt reversed).
// ---------------------------------------------------------------------------
__global__ __launch_bounds__(256)
void attn_kernel(const u16* __restrict__ qkv, const int* __restrict__ dlen,
                 u16* __restrict__ ctx)
{
    const int id = blockIdx.x;
    const int qt = 7 - (id >> 8);   // longest-first: high-qt blocks dispatch first
    const int bh = id & 255;
    const int h = bh & 7, b = bh >> 3;
    const int len = dlen[b];
    if (qt * 128 >= len) return;
    const int tid = threadIdx.x, lane = tid & 63, w = tid >> 6;
    const int quad = lane >> 4, l16 = lane & 15;
    __shared__ __align__(16) u16 Vt[2][64 * 72];   // [feat][key] pad 72, dbuf
    __shared__ __align__(16) u16 Pl[4][32 * 72];   // per-wave P [q 32][key 64]
    u16* Plw = Pl[w];
    const int sw = l16 & 3;                        // P block xor-swizzle key
    const size_t rs = 3 * Dn;
    const u16* base = qkv + (size_t)b * Sn * rs;
    const int q0 = qt * 128 + w * 32;
    constexpr float SC = 0.18033688011112043f;     // 0.125 * log2(e)

    // Q B-frags (S^T): B[k=feat][n=q]
    short8 qf[2][2];
#pragma unroll
    for (int sub = 0; sub < 2; sub++)
#pragma unroll
        for (int s = 0; s < 2; s++)
            qf[sub][s] = *(const short8*)(base + (size_t)(q0 + sub * 16 + l16) * rs
                                          + h * 64 + quad * 8 + 32 * s);

    // V staging role: 2 keys x 8 feats per thread, packed u32 writes (2-way free)
    const int key2 = (tid & 31) * 2, f0 = (tid >> 5) * 8;
    const u16* vsrc = base + 2 * Dn + h * 64 + f0;
    short8 v0 = *(const short8*)(vsrc + (size_t)key2 * rs);
    short8 v1 = *(const short8*)(vsrc + (size_t)(key2 + 1) * rs);

    // K A-frags, register double-buffered
    const u16* kbase = base + Dn + h * 64 + quad * 8;
    short8 kfb[2][4][2];
#pragma unroll
    for (int tn = 0; tn < 4; tn++) {
        const u16* kp = kbase + (size_t)(tn * 16 + l16) * rs;
        kfb[0][tn][0] = *(const short8*)kp;
        kfb[0][tn][1] = *(const short8*)(kp + 32);
    }

    short8 ones;
#pragma unroll
    for (int j = 0; j < 8; j++) ones[j] = (short)0x3F80;  // bf16 1.0

    const f32x4 vzero = {0.f, 0.f, 0.f, 0.f};
    f32x4 O[2][4], lacc[2];
#pragma unroll
    for (int sub = 0; sub < 2; sub++) {
        lacc[sub] = vzero;
#pragma unroll
        for (int t = 0; t < 4; t++) O[sub][t] = vzero;
    }

    const int nkt = (len + 63) >> 6;
    int buf = 0, kb = 0;
    for (int kt = 0; kt < nkt; kt++) {
        const int k0 = kt * 64;
        u16* Vb = Vt[buf];
#pragma unroll
        for (int j = 0; j < 8; j++)
            *(uint32_t*)&Vb[(f0 + j) * 72 + key2] =
                (uint32_t)(u16)v0[j] | ((uint32_t)(u16)v1[j] << 16);
        __syncthreads();
        if (kt + 1 < nkt) {     // prefetch next V + K (hidden behind compute)
            const u16* nv = vsrc + (size_t)(k0 + 64 + key2) * rs;
            v0 = *(const short8*)nv;
            v1 = *(const short8*)(nv + rs);
#pragma unroll
            for (int tn = 0; tn < 4; tn++) {
                const u16* kp = kbase + (size_t)(k0 + 64 + tn * 16 + l16) * rs;
                kfb[kb ^ 1][tn][0] = *(const short8*)kp;
                kfb[kb ^ 1][tn][1] = *(const short8*)(kp + 32);
            }
        }
        const bool full = (k0 + 64 <= len);
#pragma unroll
        for (int sub = 0; sub < 2; sub++) {
            f32x4 sacc[4];
#pragma unroll
            for (int tn = 0; tn < 4; tn++) {
                f32x4 z = vzero;
                z = __builtin_amdgcn_mfma_f32_16x16x32_bf16(kfb[kb][tn][0], qf[sub][0], z, 0, 0, 0);
                sacc[tn] = __builtin_amdgcn_mfma_f32_16x16x32_bf16(kfb[kb][tn][1], qf[sub][1], z, 0, 0, 0);
            }
            const int prow = (sub * 16 + l16) * 72;
#pragma unroll
            for (int tn = 0; tn < 4; tn++) {
                float p[4];
                if (full) {
#pragma unroll
                    for (int r = 0; r < 4; r++) p[r] = exp2f(sacc[tn][r] * SC);
                } else {
                    const int kbnd = k0 + tn * 16 + quad * 4;
#pragma unroll
                    for (int r = 0; r < 4; r++)
                        p[r] = (kbnd + r < len) ? exp2f(sacc[tn][r] * SC) : 0.0f;
                }
                uint2 pk;
                pk.x = (__float_as_uint(p[0]) >> 16) | (__float_as_uint(p[1]) & 0xFFFF0000u);
                pk.y = (__float_as_uint(p[2]) >> 16) | (__float_as_uint(p[3]) & 0xFFFF0000u);
                *(uint2*)&Plw[prow + (((tn ^ sw) << 4) + quad * 4)] = pk;
            }
        }
        __builtin_amdgcn_wave_barrier();   // P writes precede P reads
#pragma unroll
        for (int s = 0; s < 2; s++) {
            const int tnr = ((quad >> 1) + 2 * s) ^ sw;
            short8 pf0 = *(const short8*)&Plw[(l16) * 72 + (tnr << 4) + (quad & 1) * 8];
            short8 pf1 = *(const short8*)&Plw[(16 + l16) * 72 + (tnr << 4) + (quad & 1) * 8];
            lacc[0] = __builtin_amdgcn_mfma_f32_16x16x32_bf16(pf0, ones, lacc[0], 0, 0, 0);
            lacc[1] = __builtin_amdgcn_mfma_f32_16x16x32_bf16(pf1, ones, lacc[1], 0, 0, 0);
#pragma unroll
            for (int t = 0; t < 4; t++) {
                short8 vf = *(const short8*)&Vb[(t * 16 + l16) * 72 + quad * 8 + 32 * s];
                O[0][t] = __builtin_amdgcn_mfma_f32_16x16x32_bf16(pf0, vf, O[0][t], 0, 0, 0);
                O[1][t] = __builtin_amdgcn_mfma_f32_16x16x32_bf16(pf1, vf, O[1][t], 0, 0, 0);
            }
        }
        __builtin_amdgcn_wave_barrier();   // PV reads precede next P writes
        buf ^= 1;
        kb ^= 1;
    }
#pragma unroll
    for (int sub = 0; sub < 2; sub++)
#pragma unroll
        for (int r = 0; r < 4; r++) {
            const float inv = 1.0f / lacc[sub][r];
            const int q = q0 + sub * 16 + quad * 4 + r;
#pragma unroll
            for (int t = 0; t < 4; t++)
                ctx[(size_t)(b * Sn + q) * Dn + h * 64 + t * 16 + l16] =
                    f2b(O[sub][t][r] * inv);
        }
}

// ---------------------------------------------------------------------------
__global__ __launch_bounds__(256)
void ln_res(u16* __restrict__ x, const u16* __restrict__ t,
            const void* __restrict__ g, const void* __restrict__ bta, int off,
            const int* __restrict__ flagp, const int* __restrict__ dlen)
{
    const int w = threadIdx.x >> 6, lane = threadIdx.x & 63;
    const size_t row = (size_t)blockIdx.x * 4 + w;
    if ((int)(row & 1023) >= dlen[row >> 10]) return;
    const int F = *flagp;
    u16* xp = x + row * Dn;
    const u16* tp = t + row * Dn;
    const int c0 = lane * 8;
    short8 xv = *(const short8*)(xp + c0);
    short8 tv = *(const short8*)(tp + c0);
    float v[8]; float s = 0.f;
#pragma unroll
    for (int i = 0; i < 8; i++) {
        v[i] = b2f((u16)xv[i]) + b2f((u16)tv[i]);
        s += v[i];
    }
#pragma unroll
    for (int o = 1; o < 64; o <<= 1) s += __shfl_xor(s, o, 64);
    const float mean = s * (1.0f / 512.0f);
    float q = 0.f;
#pragma unroll
    for (int i = 0; i < 8; i++) { const float d = v[i] - mean; q += d * d; }
#pragma unroll
    for (int o = 1; o < 64; o <<= 1) q += __shfl_xor(q, o, 64);
    const float inv = rsqrtf(q * (1.0f / 512.0f) + 1e-5f);
    short8 ov;
#pragma unroll
    for (int i = 0; i < 8; i++)
        ov[i] = (short)f2b((v[i] - mean) * inv * getf(g, off + c0 + i, F)
                           + getf(bta, off + c0 + i, F));
    *(short8*)(xp + c0) = ov;
}

// ---------------------------------------------------------------------------
__global__ __launch_bounds__(256)
void embed_kernel(const void* __restrict__ loc, const void* __restrict__ tds,
                  const void* __restrict__ Wtd, const void* __restrict__ btd,
                  const void* __restrict__ Wemb, const void* __restrict__ bemb,
                  u16* __restrict__ x, const int* __restrict__ flagp,
                  const int* __restrict__ dlen)
{
    const int token = blockIdx.x;
    if ((token & 1023) >= dlen[token >> 10]) return;
    const int F = *flagp;
    const int tid = threadIdx.x;
    __shared__ float inv[19];
    if (tid < 16) {
        inv[tid] = getf(loc, (size_t)token * 16 + tid, F);
    } else if (tid < 19) {
        const int e = tid - 16;
        float a = getf(btd, e, F);
        for (int j = 0; j < 8; j++)
            a += getf(tds, (size_t)token * 8 + j, F) * getf(Wtd, j * 3 + e, F);
        inv[tid] = a;
    }
    __syncthreads();
    for (int d = tid; d < Dn; d += 256) {
        float a = getf(bemb, d, F);
#pragma unroll
        for (int i = 0; i < 19; i++) a += inv[i] * getf(Wemb, (size_t)i * Dn + d, F);
        x[(size_t)token * Dn + d] = f2b(a);
    }
}

// ---------------------------------------------------------------------------
__global__ __launch_bounds__(256)
void transpose_w(const void* __restrict__ src, u16* __restrict__ dst,
                 int K, int N, const int* __restrict__ flagp)
{
    const int F = *flagp;
    __shared__ u16 tile[32][33];
    const size_t ls = (size_t)K * N;
    const size_t sb = (size_t)blockIdx.z * ls;
    u16* d = dst + blockIdx.z * ls;
    const int tx = threadIdx.x & 31, ty = threadIdx.x >> 5;
    const int n0 = blockIdx.x * 32, k0 = blockIdx.y * 32;
#pragma unroll
    for (int i = 0; i < 32; i += 8)
        tile[ty + i][tx] = f2b(getf(src, sb + (size_t)(k0 + ty + i) * N + n0 + tx, F));
    __syncthreads();
#pragma unroll
    for (int i = 0; i < 32; i += 8)
        d[(size_t)(n0 + ty + i) * K + k0 + tx] = tile[tx][ty + i];
}

// ---------------------------------------------------------------------------
// Head: whole-block dead early-out, Wout in LDS stride 516, b64 reads.
// ---------------------------------------------------------------------------
__global__ __launch_bounds__(256)
void final_proj(const u16* __restrict__ x, const void* __restrict__ Wout,
                const void* __restrict__ Wcomb, const void* __restrict__ addr,
                const void* __restrict__ poi, const int* __restrict__ atype,
                const void* __restrict__ Wa, const void* __restrict__ ba,
                float* __restrict__ logits, const int* __restrict__ flagp,
                const int* __restrict__ dlen)
{
    const int t0 = blockIdx.x * 8;
    if ((t0 & 1023) >= dlen[t0 >> 10]) return;   // all 8 tokens dead
    const int F = *flagp;
    __shared__ float xs[8][512];
    __shared__ __align__(8) u16 wlds[32 * 516];
    const int tid = threadIdx.x;
    for (int i = tid; i < 8 * 512; i += 256) {
        const int tk = i >> 9, d = i & 511;
        xs[tk][d] = b2f(x[(size_t)(t0 + tk) * Dn + d]);
    }
    for (int i = tid; i < 16384; i += 256) {
        const int k = i >> 5, j = i & 31;
        wlds[j * 516 + k] = F ? f2b(((const float*)Wout)[(size_t)k * 32 + j])
                              : ((const u16*)Wout)[(size_t)k * 32 + j];
    }
    __syncthreads();
    const int half = tid >> 5, j = tid & 31;
    const int token = t0 + half;
    const int b = token >> 10;
    if ((token & 1023) >= dlen[b]) return;
    const int ty = atype[b];
    float a = getf(ba, j, F) + getf(addr, b, F) * getf(Wa, j, F);
#pragma unroll
    for (int e = 0; e < 3; e++)
        a += getf(poi, ty * 3 + e, F) * getf(Wa, (1 + e) * 32 + j, F);
    float s = a;
    const u16* wj = wlds + j * 516;
    const float* xr = xs[half];
#pragma unroll 4
    for (int k = 0; k < 512; k += 4) {
        const uint2 wv = *(const uint2*)&wj[k];
        s += xr[k]     * asf(wv.x << 16);
        s += xr[k + 1] * asf(wv.x & 0xFFFF0000u);
        s += xr[k + 2] * asf(wv.y << 16);
        s += xr[k + 3] * asf(wv.y & 0xFFFF0000u);
    }
    float o = tanhf(s) * getf(Wcomb, j, F);
#pragma unroll
    for (int off = 1; off < 32; off <<= 1) o += __shfl_xor(o, off, 64);
    if (j == 0) logits[token] = o;
}

// ---------------------------------------------------------------------------
__global__ __launch_bounds__(256)
void lsm_kernel(const float* __restrict__ logits, const int* __restrict__ dlen,
                float* __restrict__ out)
{
    const int b = blockIdx.x, tid = threadIdx.x;
    const int len = dlen[b];
    const float* lp = logits + (size_t)b * Sn;
    __shared__ float wA[4], wB[4];
    float mx = -3e38f;
    for (int s = tid; s < Sn; s += 256) if (s < len) mx = fmaxf(mx, lp[s]);
#pragma unroll
    for (int o = 1; o < 64; o <<= 1) mx = fmaxf(mx, __shfl_xor(mx, o, 64));
    if ((tid & 63) == 0) wA[tid >> 6] = mx;
    __syncthreads();
    mx = fmaxf(fmaxf(wA[0], wA[1]), fmaxf(wA[2], wA[3]));
    float sm = 0.f;
    for (int s = tid; s < Sn; s += 256) if (s < len) sm += __expf(lp[s] - mx);
#pragma unroll
    for (int o = 1; o < 64; o <<= 1) sm += __shfl_xor(sm, o, 64);
    if ((tid & 63) == 0) wB[tid >> 6] = sm;
    __syncthreads();
    const float lse = mx + __logf(wB[0] + wB[1] + wB[2] + wB[3]);
    for (int s = tid; s < Sn; s += 256)
        out[(size_t)b * Sn + s] = (s < len) ? (lp[s] - lse) : 0.0f;
}

// ---------------------------------------------------------------------------
extern "C" void kernel_launch(void* const* d_in, const int* in_sizes, int n_in,
                              void* d_out, int out_size, void* d_ws, size_t ws_size,
                              hipStream_t stream) {
    const void* addr  = d_in[0];
    const void* loc   = d_in[1];
    const void* tds   = d_in[2];
    const void* Wtd   = d_in[3];
    const void* btd   = d_in[4];
    const void* Wemb  = d_in[5];
    const void* bemb  = d_in[6];
    const void* Wqkv  = d_in[7];
    const void* bqkv  = d_in[8];
    const void* Wo    = d_in[9];
    const void* bo    = d_in[10];
    const void* ln1g  = d_in[11];
    const void* ln1b  = d_in[12];
    const void* W1    = d_in[13];
    const void* b1    = d_in[14];
    const void* W2    = d_in[15];
    const void* b2    = d_in[16];
    const void* ln2g  = d_in[17];
    const void* ln2b  = d_in[18];
    const void* poi   = d_in[19];
    const void* Wa    = d_in[20];
    const void* ba    = d_in[21];
    const void* Wout  = d_in[22];
    const void* Wcomb = d_in[23];
    const int* atype  = (const int*)d_in[24];
    const int* dlen   = (const int*)d_in[25];

    char* base = (char*)d_ws;
    u16*   xb    = (u16*)(base);                  // 33,554,432  x [B,S,D]
    u16*   qkvb  = (u16*)(base + 33554432ull);    // 100,663,296 qkv [B,S,3D]
    u16*   ctxb  = (u16*)(base + 134217728ull);   // 33,554,432  ctx / ff-hidden
    u16*   tb    = (u16*)(base + 167772160ull);   // 33,554,432  pre-LN GEMM out
    u16*   wqkvT = (u16*)(base + 201326592ull);   // 6,291,456
    u16*   woT   = (u16*)(base + 207618048ull);   // 2,097,152
    u16*   w1T   = (u16*)(base + 209715200ull);   // 2,097,152
    u16*   w2T   = (u16*)(base + 211812352ull);   // 2,097,152
    float* logit = (float*)(base + 213909504ull); // 131,072
    int*   flag  = (int*)  (base + 214040576ull); // 4
    if (ws_size < 214040592ull) return;

    detect_kernel<<<1, 256, 0, stream>>>(loc, flag);

    transpose_w<<<dim3(48, 16, 4), 256, 0, stream>>>(Wqkv, wqkvT, 512, 1536, flag);
    transpose_w<<<dim3(16, 16, 4), 256, 0, stream>>>(Wo,   woT,   512, 512, flag);
    transpose_w<<<dim3(16, 16, 4), 256, 0, stream>>>(W1,   w1T,   512, 512, flag);
    transpose_w<<<dim3(16, 16, 4), 256, 0, stream>>>(W2,   w2T,   512, 512, flag);

    embed_kernel<<<BS, 256, 0, stream>>>(loc, tds, Wtd, btd, Wemb, bemb, xb, flag, dlen);

    for (int l = 0; l < Ln; l++) {
        gemm_bt<<<dim3(12, 256), 256, 0, stream>>>(
            xb, wqkvT + (size_t)l * 1536 * 512, bqkv, l * 1536, qkvb, 1536, 512, 0, flag, dlen);
        attn_kernel<<<2048, 256, 0, stream>>>(qkvb, dlen, ctxb);
        gemm_bt<<<dim3(4, 256), 256, 0, stream>>>(
            ctxb, woT + (size_t)l * 512 * 512, bo, l * 512, tb, 512, 512, 0, flag, dlen);
        ln_res<<<BS / 4, 256, 0, stream>>>(xb, tb, ln1g, ln1b, l * 512, flag, dlen);
        gemm_bt<<<dim3(4, 256), 256, 0, stream>>>(
            xb, w1T + (size_t)l * 512 * 512, b1, l * 512, ctxb, 512, 512, 1, flag, dlen);
        gemm_bt<<<dim3(4, 256), 256, 0, stream>>>(
            ctxb, w2T + (size_t)l * 512 * 512, b2, l * 512, tb, 512, 512, 0, flag, dlen);
        ln_res<<<BS / 4, 256, 0, stream>>>(xb, tb, ln2g, ln2b, l * 512, flag, dlen);
    }

    final_proj<<<BS / 8, 256, 0, stream>>>(xb, Wout, Wcomb, addr, poi, atype,
                                           Wa, ba, logit, flag, dlen);
    lsm_kernel<<<Bn, 256, 0, stream>>>(logit, dlen, (float*)d_out);
}

// Round 9
// 1772.308 us; speedup vs baseline: 1.2960x; 1.2960x over previous
//
#include <hip/hip_runtime.h>
#include <stdint.h>

// LocMatcher: 4-layer post-norm transformer encoder + masked log_softmax head.
// Inputs bf16 (detector tolerates f32 via flag); OUTPUT float32.
// R9: R7 attn core (LDS V dbuf, 1 barrier/tile, S^T=K*Q^T, packed-trunc P,
// ones-MFMA denom) + longest-first order + K-prefetch with COMPILE-TIME
// buffer selection (R8's runtime-indexed register array spilled to scratch:
// WRITE_SIZE 20->424 MB; lambda with array-ref params keeps both buffers in
// VGPRs). final_proj dead-block early-out kept.

typedef unsigned short u16;
typedef __attribute__((ext_vector_type(8))) short short8;
typedef __attribute__((ext_vector_type(4))) float f32x4;

constexpr int Bn = 32, Sn = 1024, Dn = 512, Ln = 4;
constexpr int BS = Bn * Sn;

__device__ __forceinline__ float b2f(u16 u) {
    union { uint32_t i; float f; } v; v.i = ((uint32_t)u) << 16; return v.f;
}
__device__ __forceinline__ u16 f2b(float f) {
    union { float f; uint32_t i; } v; v.f = f;
    uint32_t r = v.i + 0x7fffu + ((v.i >> 16) & 1u);
    return (u16)(r >> 16);
}
__device__ __forceinline__ float getf(const void* p, size_t i, int F) {
    return F ? ((const float*)p)[i] : b2f(((const u16*)p)[i]);
}
__device__ __forceinline__ void cp16(void* lds, const void* g) {
    __builtin_amdgcn_global_load_lds(
        (__attribute__((address_space(1))) void*)(uintptr_t)g,
        (__attribute__((address_space(3))) void*)(uint32_t)(uintptr_t)lds,
        16, 0, 0);
}
__device__ __forceinline__ float asf(uint32_t u) {
    union { uint32_t i; float f; } v; v.i = u; return v.f;
}

// ---------------------------------------------------------------------------
__global__ __launch_bounds__(256)
void detect_kernel(const void* loc, int* flag)
{
    __shared__ int cnt;
    if (threadIdx.x == 0) cnt = 0;
    __syncthreads();
    const u16* p = (const u16*)loc;
    int c = 0;
    for (int i = threadIdx.x; i < 2048; i += 256) {
        const float v = b2f(p[i]);
        if (!(fabsf(v) <= 100.0f)) c++;
    }
    atomicAdd(&cnt, c);
    __syncthreads();
    if (threadIdx.x == 0) *flag = (cnt >= 64) ? 1 : 0;
}

// ---------------------------------------------------------------------------
// GEMM (m97 structure), dead 128-row M-blocks skipped.
// ---------------------------------------------------------------------------
__global__ __launch_bounds__(256)
void gemm_bt(const u16* __restrict__ A, const u16* __restrict__ Bt,
             const void* __restrict__ bias, int boff, u16* __restrict__ C,
             int N, int K, int relu, const int* __restrict__ flagp,
             const int* __restrict__ dlen)
{
    __shared__ __align__(16) u16 As[128 * 32];
    __shared__ __align__(16) u16 Bs[128 * 32];
    const int bn0 = blockIdx.x * 128, bm0 = blockIdx.y * 128;
    if ((bm0 & 1023) >= dlen[bm0 >> 10]) return;
    const int F = *flagp;
    const int tid = threadIdx.x;
    const int lane = tid & 63, w = tid >> 6;
    const int wm = w >> 1, wn = w & 1;
    const int quad = lane >> 4, l16 = lane & 15;

    const f32x4 vzero = {0.f, 0.f, 0.f, 0.f};
    f32x4 acc[4][4];
#pragma unroll
    for (int i = 0; i < 4; i++)
#pragma unroll
        for (int j = 0; j < 4; j++) acc[i][j] = vzero;

    const int i0 = tid, i1 = tid + 256;
    const u16* a0 = A + (size_t)(bm0 + (i0 >> 2)) * K + (i0 & 3) * 8;
    const u16* a1 = A + (size_t)(bm0 + (i1 >> 2)) * K + (i1 & 3) * 8;
    const u16* b0 = Bt + (size_t)(bn0 + (i0 >> 2)) * K + (i0 & 3) * 8;
    const u16* b1 = Bt + (size_t)(bn0 + (i1 >> 2)) * K + (i1 & 3) * 8;

    for (int k0 = 0; k0 < K; k0 += 32) {
        cp16(As + i0 * 8, a0 + k0);
        cp16(As + i1 * 8, a1 + k0);
        cp16(Bs + i0 * 8, b0 + k0);
        cp16(Bs + i1 * 8, b1 + k0);
        __syncthreads();
        short8 af[4], bfr[4];
#pragma unroll
        for (int t = 0; t < 4; t++)
            af[t] = *(const short8*)&As[(wm * 64 + t * 16 + l16) * 32 + quad * 8];
#pragma unroll
        for (int t = 0; t < 4; t++)
            bfr[t] = *(const short8*)&Bs[(wn * 64 + t * 16 + l16) * 32 + quad * 8];
#pragma unroll
        for (int tm = 0; tm < 4; tm++)
#pragma unroll
            for (int tn = 0; tn < 4; tn++)
                acc[tm][tn] = __builtin_amdgcn_mfma_f32_16x16x32_bf16(
                    af[tm], bfr[tn], acc[tm][tn], 0, 0, 0);
        __syncthreads();
    }
#pragma unroll
    for (int tm = 0; tm < 4; tm++)
#pragma unroll
        for (int tn = 0; tn < 4; tn++) {
            const int col = bn0 + wn * 64 + tn * 16 + l16;
            const float bv = getf(bias, (size_t)boff + col, F);
#pragma unroll
            for (int r = 0; r < 4; r++) {
                const int row = bm0 + wm * 64 + tm * 16 + quad * 4 + r;
                float v = acc[tm][tn][r] + bv;
                if (relu) v = fmaxf(v, 0.0f);
                C[(size_t)row * N + col] = f2b(v);
            }
        }
}

// ---------------------------------------------------------------------------
// Flash attention v6: R7 core + longest-first + static K double-buffer.
// ---------------------------------------------------------------------------
__global__ __launch_bounds__(256)
void attn_kernel(const u16* __restrict__ qkv, const int* __restrict__ dlen,
                 u16* __restrict__ ctx)
{
    const int id = blockIdx.x;
    const int qt = 7 - (id >> 8);   // longest-first
    const int bh = id & 255;
    const int h = bh & 7, b = bh >> 3;
    const int len = dlen[b];
    if (qt * 128 >= len) return;
    const int tid = threadIdx.x, lane = tid & 63, w = tid >> 6;
    const int quad = lane >> 4, l16 = lane & 15;
    __shared__ __align__(16) u16 Vt[2][64 * 72];   // [feat][key] pad 72, dbuf
    __shared__ __align__(16) u16 Pl[4][32 * 72];   // per-wave P [q 32][key 64]
    u16* Plw = Pl[w];
    const int sw = l16 & 3;
    const size_t rs = 3 * Dn;
    const u16* base = qkv + (size_t)b * Sn * rs;
    const int q0 = qt * 128 + w * 32;
    constexpr float SC = 0.18033688011112043f;     // 0.125 * log2(e)

    // Q B-frags (S^T): B[k=feat][n=q]
    short8 qf[2][2];
#pragma unroll
    for (int sub = 0; sub < 2; sub++)
#pragma unroll
        for (int s = 0; s < 2; s++)
            qf[sub][s] = *(const short8*)(base + (size_t)(q0 + sub * 16 + l16) * rs
                                          + h * 64 + quad * 8 + 32 * s);

    // V staging role: 2 keys x 8 feats, packed u32 writes (2-way free)
    const int key2 = (tid & 31) * 2, f0 = (tid >> 5) * 8;
    const u16* vsrc = base + 2 * Dn + h * 64 + f0;
    short8 v0 = *(const short8*)(vsrc + (size_t)key2 * rs);
    short8 v1 = *(const short8*)(vsrc + (size_t)(key2 + 1) * rs);

    // K A-frags: two STATICALLY-selected buffers (no runtime indexing ->
    // stays in VGPRs; R8's kfb[kb] spilled to scratch).
    const u16* kbase = base + Dn + h * 64 + quad * 8;
    short8 kfA[4][2], kfB[4][2];
#pragma unroll
    for (int tn = 0; tn < 4; tn++) {
        const u16* kp = kbase + (size_t)(tn * 16 + l16) * rs;
        kfA[tn][0] = *(const short8*)kp;
        kfA[tn][1] = *(const short8*)(kp + 32);
    }

    short8 ones;
#pragma unroll
    for (int j = 0; j < 8; j++) ones[j] = (short)0x3F80;  // bf16 1.0

    const f32x4 vzero = {0.f, 0.f, 0.f, 0.f};
    f32x4 O[2][4], lacc[2];
#pragma unroll
    for (int sub = 0; sub < 2; sub++) {
        lacc[sub] = vzero;
#pragma unroll
        for (int t = 0; t < 4; t++) O[sub][t] = vzero;
    }

    const int nkt = (len + 63) >> 6;

    auto tile = [&](int kt, short8 (&kfu)[4][2], short8 (&kfn)[4][2]) {
        const int k0 = kt * 64;
        u16* Vb = Vt[kt & 1];
#pragma unroll
        for (int j = 0; j < 8; j++)
            *(uint32_t*)&Vb[(f0 + j) * 72 + key2] =
                (uint32_t)(u16)v0[j] | ((uint32_t)(u16)v1[j] << 16);
        __syncthreads();
        if (kt + 1 < nkt) {   // prefetch next V + K into the OTHER buffer
            const u16* nv = vsrc + (size_t)(k0 + 64 + key2) * rs;
            v0 = *(const short8*)nv;
            v1 = *(const short8*)(nv + rs);
#pragma unroll
            for (int tn = 0; tn < 4; tn++) {
                const u16* kp = kbase + (size_t)(k0 + 64 + tn * 16 + l16) * rs;
                kfn[tn][0] = *(const short8*)kp;
                kfn[tn][1] = *(const short8*)(kp + 32);
            }
        }
        const bool full = (k0 + 64 <= len);
#pragma unroll
        for (int sub = 0; sub < 2; sub++) {
            f32x4 sacc[4];
#pragma unroll
            for (int tn = 0; tn < 4; tn++) {
                f32x4 z = vzero;
                z = __builtin_amdgcn_mfma_f32_16x16x32_bf16(kfu[tn][0], qf[sub][0], z, 0, 0, 0);
                sacc[tn] = __builtin_amdgcn_mfma_f32_16x16x32_bf16(kfu[tn][1], qf[sub][1], z, 0, 0, 0);
            }
            const int prow = (sub * 16 + l16) * 72;
#pragma unroll
            for (int tn = 0; tn < 4; tn++) {
                float p[4];
                if (full) {
#pragma unroll
                    for (int r = 0; r < 4; r++) p[r] = exp2f(sacc[tn][r] * SC);
                } else {
                    const int kbnd = k0 + tn * 16 + quad * 4;
#pragma unroll
                    for (int r = 0; r < 4; r++)
                        p[r] = (kbnd + r < len) ? exp2f(sacc[tn][r] * SC) : 0.0f;
                }
                uint2 pk;
                pk.x = (__float_as_uint(p[0]) >> 16) | (__float_as_uint(p[1]) & 0xFFFF0000u);
                pk.y = (__float_as_uint(p[2]) >> 16) | (__float_as_uint(p[3]) & 0xFFFF0000u);
                *(uint2*)&Plw[prow + (((tn ^ sw) << 4) + quad * 4)] = pk;
            }
        }
        __builtin_amdgcn_wave_barrier();   // P writes precede P reads
#pragma unroll
        for (int s = 0; s < 2; s++) {
            const int tnr = ((quad >> 1) + 2 * s) ^ sw;
            short8 pf0 = *(const short8*)&Plw[(l16) * 72 + (tnr << 4) + (quad & 1) * 8];
            short8 pf1 = *(const short8*)&Plw[(16 + l16) * 72 + (tnr << 4) + (quad & 1) * 8];
            lacc[0] = __builtin_amdgcn_mfma_f32_16x16x32_bf16(pf0, ones, lacc[0], 0, 0, 0);
            lacc[1] = __builtin_amdgcn_mfma_f32_16x16x32_bf16(pf1, ones, lacc[1], 0, 0, 0);
#pragma unroll
            for (int t = 0; t < 4; t++) {
                short8 vf = *(const short8*)&Vb[(t * 16 + l16) * 72 + quad * 8 + 32 * s];
                O[0][t] = __builtin_amdgcn_mfma_f32_16x16x32_bf16(pf0, vf, O[0][t], 0, 0, 0);
                O[1][t] = __builtin_amdgcn_mfma_f32_16x16x32_bf16(pf1, vf, O[1][t], 0, 0, 0);
            }
        }
        __builtin_amdgcn_wave_barrier();   // PV reads precede next P writes
    };

    for (int kt = 0; kt < nkt; kt += 2) {
        tile(kt, kfA, kfB);
        if (kt + 1 < nkt) tile(kt + 1, kfB, kfA);
    }

#pragma unroll
    for (int sub = 0; sub < 2; sub++)
#pragma unroll
        for (int r = 0; r < 4; r++) {
            const float inv = 1.0f / lacc[sub][r];
            const int q = q0 + sub * 16 + quad * 4 + r;
#pragma unroll
            for (int t = 0; t < 4; t++)
                ctx[(size_t)(b * Sn + q) * Dn + h * 64 + t * 16 + l16] =
                    f2b(O[sub][t][r] * inv);
        }
}

// ---------------------------------------------------------------------------
__global__ __launch_bounds__(256)
void ln_res(u16* __restrict__ x, const u16* __restrict__ t,
            const void* __restrict__ g, const void* __restrict__ bta, int off,
            const int* __restrict__ flagp, const int* __restrict__ dlen)
{
    const int w = threadIdx.x >> 6, lane = threadIdx.x & 63;
    const size_t row = (size_t)blockIdx.x * 4 + w;
    if ((int)(row & 1023) >= dlen[row >> 10]) return;
    const int F = *flagp;
    u16* xp = x + row * Dn;
    const u16* tp = t + row * Dn;
    const int c0 = lane * 8;
    short8 xv = *(const short8*)(xp + c0);
    short8 tv = *(const short8*)(tp + c0);
    float v[8]; float s = 0.f;
#pragma unroll
    for (int i = 0; i < 8; i++) {
        v[i] = b2f((u16)xv[i]) + b2f((u16)tv[i]);
        s += v[i];
    }
#pragma unroll
    for (int o = 1; o < 64; o <<= 1) s += __shfl_xor(s, o, 64);
    const float mean = s * (1.0f / 512.0f);
    float q = 0.f;
#pragma unroll
    for (int i = 0; i < 8; i++) { const float d = v[i] - mean; q += d * d; }
#pragma unroll
    for (int o = 1; o < 64; o <<= 1) q += __shfl_xor(q, o, 64);
    const float inv = rsqrtf(q * (1.0f / 512.0f) + 1e-5f);
    short8 ov;
#pragma unroll
    for (int i = 0; i < 8; i++)
        ov[i] = (short)f2b((v[i] - mean) * inv * getf(g, off + c0 + i, F)
                           + getf(bta, off + c0 + i, F));
    *(short8*)(xp + c0) = ov;
}

// ---------------------------------------------------------------------------
__global__ __launch_bounds__(256)
void embed_kernel(const void* __restrict__ loc, const void* __restrict__ tds,
                  const void* __restrict__ Wtd, const void* __restrict__ btd,
                  const void* __restrict__ Wemb, const void* __restrict__ bemb,
                  u16* __restrict__ x, const int* __restrict__ flagp,
                  const int* __restrict__ dlen)
{
    const int token = blockIdx.x;
    if ((token & 1023) >= dlen[token >> 10]) return;
    const int F = *flagp;
    const int tid = threadIdx.x;
    __shared__ float inv[19];
    if (tid < 16) {
        inv[tid] = getf(loc, (size_t)token * 16 + tid, F);
    } else if (tid < 19) {
        const int e = tid - 16;
        float a = getf(btd, e, F);
        for (int j = 0; j < 8; j++)
            a += getf(tds, (size_t)token * 8 + j, F) * getf(Wtd, j * 3 + e, F);
        inv[tid] = a;
    }
    __syncthreads();
    for (int d = tid; d < Dn; d += 256) {
        float a = getf(bemb, d, F);
#pragma unroll
        for (int i = 0; i < 19; i++) a += inv[i] * getf(Wemb, (size_t)i * Dn + d, F);
        x[(size_t)token * Dn + d] = f2b(a);
    }
}

// ---------------------------------------------------------------------------
__global__ __launch_bounds__(256)
void transpose_w(const void* __restrict__ src, u16* __restrict__ dst,
                 int K, int N, const int* __restrict__ flagp)
{
    const int F = *flagp;
    __shared__ u16 tile[32][33];
    const size_t ls = (size_t)K * N;
    const size_t sb = (size_t)blockIdx.z * ls;
    u16* d = dst + blockIdx.z * ls;
    const int tx = threadIdx.x & 31, ty = threadIdx.x >> 5;
    const int n0 = blockIdx.x * 32, k0 = blockIdx.y * 32;
#pragma unroll
    for (int i = 0; i < 32; i += 8)
        tile[ty + i][tx] = f2b(getf(src, sb + (size_t)(k0 + ty + i) * N + n0 + tx, F));
    __syncthreads();
#pragma unroll
    for (int i = 0; i < 32; i += 8)
        d[(size_t)(n0 + ty + i) * K + k0 + tx] = tile[tx][ty + i];
}

// ---------------------------------------------------------------------------
// Head: whole-block dead early-out, Wout in LDS stride 516, b64 reads.
// ---------------------------------------------------------------------------
__global__ __launch_bounds__(256)
void final_proj(const u16* __restrict__ x, const void* __restrict__ Wout,
                const void* __restrict__ Wcomb, const void* __restrict__ addr,
                const void* __restrict__ poi, const int* __restrict__ atype,
                const void* __restrict__ Wa, const void* __restrict__ ba,
                float* __restrict__ logits, const int* __restrict__ flagp,
                const int* __restrict__ dlen)
{
    const int t0 = blockIdx.x * 8;
    if ((t0 & 1023) >= dlen[t0 >> 10]) return;   // all 8 tokens dead
    const int F = *flagp;
    __shared__ float xs[8][512];
    __shared__ __align__(8) u16 wlds[32 * 516];
    const int tid = threadIdx.x;
    for (int i = tid; i < 8 * 512; i += 256) {
        const int tk = i >> 9, d = i & 511;
        xs[tk][d] = b2f(x[(size_t)(t0 + tk) * Dn + d]);
    }
    for (int i = tid; i < 16384; i += 256) {
        const int k = i >> 5, j = i & 31;
        wlds[j * 516 + k] = F ? f2b(((const float*)Wout)[(size_t)k * 32 + j])
                              : ((const u16*)Wout)[(size_t)k * 32 + j];
    }
    __syncthreads();
    const int half = tid >> 5, j = tid & 31;
    const int token = t0 + half;
    const int b = token >> 10;
    if ((token & 1023) >= dlen[b]) return;
    const int ty = atype[b];
    float a = getf(ba, j, F) + getf(addr, b, F) * getf(Wa, j, F);
#pragma unroll
    for (int e = 0; e < 3; e++)
        a += getf(poi, ty * 3 + e, F) * getf(Wa, (1 + e) * 32 + j, F);
    float s = a;
    const u16* wj = wlds + j * 516;
    const float* xr = xs[half];
#pragma unroll 4
    for (int k = 0; k < 512; k += 4) {
        const uint2 wv = *(const uint2*)&wj[k];
        s += xr[k]     * asf(wv.x << 16);
        s += xr[k + 1] * asf(wv.x & 0xFFFF0000u);
        s += xr[k + 2] * asf(wv.y << 16);
        s += xr[k + 3] * asf(wv.y & 0xFFFF0000u);
    }
    float o = tanhf(s) * getf(Wcomb, j, F);
#pragma unroll
    for (int off = 1; off < 32; off <<= 1) o += __shfl_xor(o, off, 64);
    if (j == 0) logits[token] = o;
}

// ---------------------------------------------------------------------------
__global__ __launch_bounds__(256)
void lsm_kernel(const float* __restrict__ logits, const int* __restrict__ dlen,
                float* __restrict__ out)
{
    const int b = blockIdx.x, tid = threadIdx.x;
    const int len = dlen[b];
    const float* lp = logits + (size_t)b * Sn;
    __shared__ float wA[4], wB[4];
    float mx = -3e38f;
    for (int s = tid; s < Sn; s += 256) if (s < len) mx = fmaxf(mx, lp[s]);
#pragma unroll
    for (int o = 1; o < 64; o <<= 1) mx = fmaxf(mx, __shfl_xor(mx, o, 64));
    if ((tid & 63) == 0) wA[tid >> 6] = mx;
    __syncthreads();
    mx = fmaxf(fmaxf(wA[0], wA[1]), fmaxf(wA[2], wA[3]));
    float sm = 0.f;
    for (int s = tid; s < Sn; s += 256) if (s < len) sm += __expf(lp[s] - mx);
#pragma unroll
    for (int o = 1; o < 64; o <<= 1) sm += __shfl_xor(sm, o, 64);
    if ((tid & 63) == 0) wB[tid >> 6] = sm;
    __syncthreads();
    const float lse = mx + __logf(wB[0] + wB[1] + wB[2] + wB[3]);
    for (int s = tid; s < Sn; s += 256)
        out[(size_t)b * Sn + s] = (s < len) ? (lp[s] - lse) : 0.0f;
}

// ---------------------------------------------------------------------------
extern "C" void kernel_launch(void* const* d_in, const int* in_sizes, int n_in,
                              void* d_out, int out_size, void* d_ws, size_t ws_size,
                              hipStream_t stream) {
    const void* addr  = d_in[0];
    const void* loc   = d_in[1];
    const void* tds   = d_in[2];
    const void* Wtd   = d_in[3];
    const void* btd   = d_in[4];
    const void* Wemb  = d_in[5];
    const void* bemb  = d_in[6];
    const void* Wqkv  = d_in[7];
    const void* bqkv  = d_in[8];
    const void* Wo    = d_in[9];
    const void* bo    = d_in[10];
    const void* ln1g  = d_in[11];
    const void* ln1b  = d_in[12];
    const void* W1    = d_in[13];
    const void* b1    = d_in[14];
    const void* W2    = d_in[15];
    const void* b2    = d_in[16];
    const void* ln2g  = d_in[17];
    const void* ln2b  = d_in[18];
    const void* poi   = d_in[19];
    const void* Wa    = d_in[20];
    const void* ba    = d_in[21];
    const void* Wout  = d_in[22];
    const void* Wcomb = d_in[23];
    const int* atype  = (const int*)d_in[24];
    const int* dlen   = (const int*)d_in[25];

    char* base = (char*)d_ws;
    u16*   xb    = (u16*)(base);                  // 33,554,432  x [B,S,D]
    u16*   qkvb  = (u16*)(base + 33554432ull);    // 100,663,296 qkv [B,S,3D]
    u16*   ctxb  = (u16*)(base + 134217728ull);   // 33,554,432  ctx / ff-hidden
    u16*   tb    = (u16*)(base + 167772160ull);   // 33,554,432  pre-LN GEMM out
    u16*   wqkvT = (u16*)(base + 201326592ull);   // 6,291,456
    u16*   woT   = (u16*)(base + 207618048ull);   // 2,097,152
    u16*   w1T   = (u16*)(base + 209715200ull);   // 2,097,152
    u16*   w2T   = (u16*)(base + 211812352ull);   // 2,097,152
    float* logit = (float*)(base + 213909504ull); // 131,072
    int*   flag  = (int*)  (base + 214040576ull); // 4
    if (ws_size < 214040592ull) return;

    detect_kernel<<<1, 256, 0, stream>>>(loc, flag);

    transpose_w<<<dim3(48, 16, 4), 256, 0, stream>>>(Wqkv, wqkvT, 512, 1536, flag);
    transpose_w<<<dim3(16, 16, 4), 256, 0, stream>>>(Wo,   woT,   512, 512, flag);
    transpose_w<<<dim3(16, 16, 4), 256, 0, stream>>>(W1,   w1T,   512, 512, flag);
    transpose_w<<<dim3(16, 16, 4), 256, 0, stream>>>(W2,   w2T,   512, 512, flag);

    embed_kernel<<<BS, 256, 0, stream>>>(loc, tds, Wtd, btd, Wemb, bemb, xb, flag, dlen);

    for (int l = 0; l < Ln; l++) {
        gemm_bt<<<dim3(12, 256), 256, 0, stream>>>(
            xb, wqkvT + (size_t)l * 1536 * 512, bqkv, l * 1536, qkvb, 1536, 512, 0, flag, dlen);
        attn_kernel<<<2048, 256, 0, stream>>>(qkvb, dlen, ctxb);
        gemm_bt<<<dim3(4, 256), 256, 0, stream>>>(
            ctxb, woT + (size_t)l * 512 * 512, bo, l * 512, tb, 512, 512, 0, flag, dlen);
        ln_res<<<BS / 4, 256, 0, stream>>>(xb, tb, ln1g, ln1b, l * 512, flag, dlen);
        gemm_bt<<<dim3(4, 256), 256, 0, stream>>>(
            xb, w1T + (size_t)l * 512 * 512, b1, l * 512, ctxb, 512, 512, 1, flag, dlen);
        gemm_bt<<<dim3(4, 256), 256, 0, stream>>>(
            ctxb, w2T + (size_t)l * 512 * 512, b2, l * 512, tb, 512, 512, 0, flag, dlen);
        ln_res<<<BS / 4, 256, 0, stream>>>(xb, tb, ln2g, ln2b, l * 512, flag, dlen);
    }

    final_proj<<<BS / 8, 256, 0, stream>>>(xb, Wout, Wcomb, addr, poi, atype,
                                           Wa, ba, logit, flag, dlen);
    lsm_kernel<<<Bn, 256, 0, stream>>>(logit, dlen, (float*)d_out);
}

// Round 10
// 1737.212 us; speedup vs baseline: 1.3222x; 1.0202x over previous
//
#include <hip/hip_runtime.h>
#include <stdint.h>

// LocMatcher: 4-layer post-norm transformer encoder + masked log_softmax head.
// Inputs bf16 (detector tolerates f32 via flag); OUTPUT float32.
// R10: QKV GEMM epilogue scatters into per-head PACKED buffers qp/kp/vp
// [b*8+h][s][64] -> attention K/V/Q loads become fully coalesced (R9 showed
// attn is exposed-HBM-latency bound on 3KB-stride gathers: 474 GB/s effective,
// 135us). Attn core = R7 flow (LDS V dbuf, 1 barrier/tile, S^T=K*Q^T,
// packed-trunc P, ones-MFMA denom); K reg-dbuf dropped (R9: neutral, +40 VGPR).

typedef unsigned short u16;
typedef __attribute__((ext_vector_type(8))) short short8;
typedef __attribute__((ext_vector_type(4))) float f32x4;

constexpr int Bn = 32, Sn = 1024, Dn = 512, Ln = 4;
constexpr int BS = Bn * Sn;
constexpr size_t QKV_OFF = 16777216; // elems per packed tensor (32 MB bf16)

__device__ __forceinline__ float b2f(u16 u) {
    union { uint32_t i; float f; } v; v.i = ((uint32_t)u) << 16; return v.f;
}
__device__ __forceinline__ u16 f2b(float f) {
    union { float f; uint32_t i; } v; v.f = f;
    uint32_t r = v.i + 0x7fffu + ((v.i >> 16) & 1u);
    return (u16)(r >> 16);
}
__device__ __forceinline__ float getf(const void* p, size_t i, int F) {
    return F ? ((const float*)p)[i] : b2f(((const u16*)p)[i]);
}
__device__ __forceinline__ void cp16(void* lds, const void* g) {
    __builtin_amdgcn_global_load_lds(
        (__attribute__((address_space(1))) void*)(uintptr_t)g,
        (__attribute__((address_space(3))) void*)(uint32_t)(uintptr_t)lds,
        16, 0, 0);
}
__device__ __forceinline__ float asf(uint32_t u) {
    union { uint32_t i; float f; } v; v.i = u; return v.f;
}

// ---------------------------------------------------------------------------
__global__ __launch_bounds__(256)
void detect_kernel(const void* loc, int* flag)
{
    __shared__ int cnt;
    if (threadIdx.x == 0) cnt = 0;
    __syncthreads();
    const u16* p = (const u16*)loc;
    int c = 0;
    for (int i = threadIdx.x; i < 2048; i += 256) {
        const float v = b2f(p[i]);
        if (!(fabsf(v) <= 100.0f)) c++;
    }
    atomicAdd(&cnt, c);
    __syncthreads();
    if (threadIdx.x == 0) *flag = (cnt >= 64) ? 1 : 0;
}

// ---------------------------------------------------------------------------
// GEMM (m97 structure), dead 128-row M-blocks skipped.
// mode 0: C[row*N+col]. mode 1 (QKV): scatter into packed qp/kp/vp
// [(b*8+h)<<16 | s*64 | f] with qp=C, kp=C+QKV_OFF, vp=C+2*QKV_OFF.
// ---------------------------------------------------------------------------
__global__ __launch_bounds__(256)
void gemm_bt(const u16* __restrict__ A, const u16* __restrict__ Bt,
             const void* __restrict__ bias, int boff, u16* __restrict__ C,
             int N, int K, int relu, int mode, const int* __restrict__ flagp,
             const int* __restrict__ dlen)
{
    __shared__ __align__(16) u16 As[128 * 32];
    __shared__ __align__(16) u16 Bs[128 * 32];
    const int bn0 = blockIdx.x * 128, bm0 = blockIdx.y * 128;
    if ((bm0 & 1023) >= dlen[bm0 >> 10]) return;
    const int F = *flagp;
    const int tid = threadIdx.x;
    const int lane = tid & 63, w = tid >> 6;
    const int wm = w >> 1, wn = w & 1;
    const int quad = lane >> 4, l16 = lane & 15;

    const f32x4 vzero = {0.f, 0.f, 0.f, 0.f};
    f32x4 acc[4][4];
#pragma unroll
    for (int i = 0; i < 4; i++)
#pragma unroll
        for (int j = 0; j < 4; j++) acc[i][j] = vzero;

    const int i0 = tid, i1 = tid + 256;
    const u16* a0 = A + (size_t)(bm0 + (i0 >> 2)) * K + (i0 & 3) * 8;
    const u16* a1 = A + (size_t)(bm0 + (i1 >> 2)) * K + (i1 & 3) * 8;
    const u16* b0 = Bt + (size_t)(bn0 + (i0 >> 2)) * K + (i0 & 3) * 8;
    const u16* b1 = Bt + (size_t)(bn0 + (i1 >> 2)) * K + (i1 & 3) * 8;

    for (int k0 = 0; k0 < K; k0 += 32) {
        cp16(As + i0 * 8, a0 + k0);
        cp16(As + i1 * 8, a1 + k0);
        cp16(Bs + i0 * 8, b0 + k0);
        cp16(Bs + i1 * 8, b1 + k0);
        __syncthreads();
        short8 af[4], bfr[4];
#pragma unroll
        for (int t = 0; t < 4; t++)
            af[t] = *(const short8*)&As[(wm * 64 + t * 16 + l16) * 32 + quad * 8];
#pragma unroll
        for (int t = 0; t < 4; t++)
            bfr[t] = *(const short8*)&Bs[(wn * 64 + t * 16 + l16) * 32 + quad * 8];
#pragma unroll
        for (int tm = 0; tm < 4; tm++)
#pragma unroll
            for (int tn = 0; tn < 4; tn++)
                acc[tm][tn] = __builtin_amdgcn_mfma_f32_16x16x32_bf16(
                    af[tm], bfr[tn], acc[tm][tn], 0, 0, 0);
        __syncthreads();
    }
    const int bb = bm0 >> 10;  // batch (128 | 1024, block never straddles)
#pragma unroll
    for (int tm = 0; tm < 4; tm++)
#pragma unroll
        for (int tn = 0; tn < 4; tn++) {
            const int col = bn0 + wn * 64 + tn * 16 + l16;
            const float bv = getf(bias, (size_t)boff + col, F);
            if (mode == 0) {
#pragma unroll
                for (int r = 0; r < 4; r++) {
                    const int row = bm0 + wm * 64 + tm * 16 + quad * 4 + r;
                    float v = acc[tm][tn][r] + bv;
                    if (relu) v = fmaxf(v, 0.0f);
                    C[(size_t)row * N + col] = f2b(v);
                }
            } else {
                const int which = col >> 9;      // 0=q 1=k 2=v
                const int c = col & 511;
                const int hh = c >> 6, f = c & 63;
                u16* dst = C + (size_t)which * QKV_OFF
                           + (((size_t)(bb * 8 + hh)) << 16) + f;
#pragma unroll
                for (int r = 0; r < 4; r++) {
                    const int s = (bm0 & 1023) + wm * 64 + tm * 16 + quad * 4 + r;
                    dst[(size_t)s * 64] = f2b(acc[tm][tn][r] + bv);
                }
            }
        }
}

// ---------------------------------------------------------------------------
// Flash attention v7: packed per-head Q/K/V (fully coalesced loads), R7 core:
// 128 q/block, LDS V dbuf (1 barrier/tile), S^T=K*Q^T, swizzled packed-trunc
// P, ones-MFMA denom, longest-first block order.
// ---------------------------------------------------------------------------
__global__ __launch_bounds__(256)
void attn_kernel(const u16* __restrict__ qp, const int* __restrict__ dlen,
                 u16* __restrict__ ctx)
{
    const int id = blockIdx.x;
    const int qt = 7 - (id >> 8);   // longest-first
    const int bh = id & 255;
    const int h = bh & 7, b = bh >> 3;
    const int len = dlen[b];
    if (qt * 128 >= len) return;
    const int tid = threadIdx.x, lane = tid & 63, w = tid >> 6;
    const int quad = lane >> 4, l16 = lane & 15;
    __shared__ __align__(16) u16 Vt[2][64 * 72];   // [feat][key] pad 72, dbuf
    __shared__ __align__(16) u16 Pl[4][32 * 72];   // per-wave P [q 32][key 64]
    u16* Plw = Pl[w];
    const int sw = l16 & 3;
    const u16* qb = qp + ((size_t)bh << 16);       // [s][64]
    const u16* kb = qb + QKV_OFF;
    const u16* vb = qb + 2 * QKV_OFF;
    const int q0 = qt * 128 + w * 32;
    constexpr float SC = 0.18033688011112043f;     // 0.125 * log2(e)

    // Q B-frags (S^T): B[k=feat][n=q] — contiguous 128B rows
    short8 qf[2][2];
#pragma unroll
    for (int sub = 0; sub < 2; sub++)
#pragma unroll
        for (int s = 0; s < 2; s++)
            qf[sub][s] = *(const short8*)(qb + (size_t)(q0 + sub * 16 + l16) * 64
                                          + quad * 8 + 32 * s);

    // V staging: 2 keys x 8 feats per thread, packed u32 LDS writes
    const int key2 = (tid & 31) * 2, f0 = (tid >> 5) * 8;
    const u16* vsrc = vb + f0;
    short8 v0 = *(const short8*)(vsrc + (size_t)key2 * 64);
    short8 v1 = *(const short8*)(vsrc + (size_t)(key2 + 1) * 64);

    short8 ones;
#pragma unroll
    for (int j = 0; j < 8; j++) ones[j] = (short)0x3F80;  // bf16 1.0

    const f32x4 vzero = {0.f, 0.f, 0.f, 0.f};
    f32x4 O[2][4], lacc[2];
#pragma unroll
    for (int sub = 0; sub < 2; sub++) {
        lacc[sub] = vzero;
#pragma unroll
        for (int t = 0; t < 4; t++) O[sub][t] = vzero;
    }

    const int nkt = (len + 63) >> 6;
    int buf = 0;
    for (int kt = 0; kt < nkt; kt++) {
        const int k0 = kt * 64;
        u16* Vb = Vt[buf];
#pragma unroll
        for (int j = 0; j < 8; j++)
            *(uint32_t*)&Vb[(f0 + j) * 72 + key2] =
                (uint32_t)(u16)v0[j] | ((uint32_t)(u16)v1[j] << 16);
        __syncthreads();
        if (kt + 1 < nkt) {   // prefetch next V tile
            const u16* nv = vsrc + (size_t)(k0 + 64 + key2) * 64;
            v0 = *(const short8*)nv;
            v1 = *(const short8*)(nv + 64);
        }
        // K A-frags: 16 keys x 64 feats = 2KB contiguous per tn
        short8 kf[4][2];
#pragma unroll
        for (int tn = 0; tn < 4; tn++) {
            const u16* kp2 = kb + (size_t)(k0 + tn * 16 + l16) * 64 + quad * 8;
            kf[tn][0] = *(const short8*)kp2;
            kf[tn][1] = *(const short8*)(kp2 + 32);
        }
        const bool full = (k0 + 64 <= len);
#pragma unroll
        for (int sub = 0; sub < 2; sub++) {
            f32x4 sacc[4];
#pragma unroll
            for (int tn = 0; tn < 4; tn++) {
                f32x4 z = vzero;
                z = __builtin_amdgcn_mfma_f32_16x16x32_bf16(kf[tn][0], qf[sub][0], z, 0, 0, 0);
                sacc[tn] = __builtin_amdgcn_mfma_f32_16x16x32_bf16(kf[tn][1], qf[sub][1], z, 0, 0, 0);
            }
            const int prow = (sub * 16 + l16) * 72;
#pragma unroll
            for (int tn = 0; tn < 4; tn++) {
                float p[4];
                if (full) {
#pragma unroll
                    for (int r = 0; r < 4; r++) p[r] = exp2f(sacc[tn][r] * SC);
                } else {
                    const int kbnd = k0 + tn * 16 + quad * 4;
#pragma unroll
                    for (int r = 0; r < 4; r++)
                        p[r] = (kbnd + r < len) ? exp2f(sacc[tn][r] * SC) : 0.0f;
                }
                uint2 pk;
                pk.x = (__float_as_uint(p[0]) >> 16) | (__float_as_uint(p[1]) & 0xFFFF0000u);
                pk.y = (__float_as_uint(p[2]) >> 16) | (__float_as_uint(p[3]) & 0xFFFF0000u);
                *(uint2*)&Plw[prow + (((tn ^ sw) << 4) + quad * 4)] = pk;
            }
        }
        __builtin_amdgcn_wave_barrier();   // P writes precede P reads
#pragma unroll
        for (int s = 0; s < 2; s++) {
            const int tnr = ((quad >> 1) + 2 * s) ^ sw;
            short8 pf0 = *(const short8*)&Plw[(l16) * 72 + (tnr << 4) + (quad & 1) * 8];
            short8 pf1 = *(const short8*)&Plw[(16 + l16) * 72 + (tnr << 4) + (quad & 1) * 8];
            lacc[0] = __builtin_amdgcn_mfma_f32_16x16x32_bf16(pf0, ones, lacc[0], 0, 0, 0);
            lacc[1] = __builtin_amdgcn_mfma_f32_16x16x32_bf16(pf1, ones, lacc[1], 0, 0, 0);
#pragma unroll
            for (int t = 0; t < 4; t++) {
                short8 vf = *(const short8*)&Vb[(t * 16 + l16) * 72 + quad * 8 + 32 * s];
                O[0][t] = __builtin_amdgcn_mfma_f32_16x16x32_bf16(pf0, vf, O[0][t], 0, 0, 0);
                O[1][t] = __builtin_amdgcn_mfma_f32_16x16x32_bf16(pf1, vf, O[1][t], 0, 0, 0);
            }
        }
        __builtin_amdgcn_wave_barrier();   // PV reads precede next P writes
        buf ^= 1;
    }
#pragma unroll
    for (int sub = 0; sub < 2; sub++)
#pragma unroll
        for (int r = 0; r < 4; r++) {
            const float inv = 1.0f / lacc[sub][r];
            const int q = q0 + sub * 16 + quad * 4 + r;
#pragma unroll
            for (int t = 0; t < 4; t++)
                ctx[(size_t)(b * Sn + q) * Dn + h * 64 + t * 16 + l16] =
                    f2b(O[sub][t][r] * inv);
        }
}

// ---------------------------------------------------------------------------
__global__ __launch_bounds__(256)
void ln_res(u16* __restrict__ x, const u16* __restrict__ t,
            const void* __restrict__ g, const void* __restrict__ bta, int off,
            const int* __restrict__ flagp, const int* __restrict__ dlen)
{
    const int w = threadIdx.x >> 6, lane = threadIdx.x & 63;
    const size_t row = (size_t)blockIdx.x * 4 + w;
    if ((int)(row & 1023) >= dlen[row >> 10]) return;
    const int F = *flagp;
    u16* xp = x + row * Dn;
    const u16* tp = t + row * Dn;
    const int c0 = lane * 8;
    short8 xv = *(const short8*)(xp + c0);
    short8 tv = *(const short8*)(tp + c0);
    float v[8]; float s = 0.f;
#pragma unroll
    for (int i = 0; i < 8; i++) {
        v[i] = b2f((u16)xv[i]) + b2f((u16)tv[i]);
        s += v[i];
    }
#pragma unroll
    for (int o = 1; o < 64; o <<= 1) s += __shfl_xor(s, o, 64);
    const float mean = s * (1.0f / 512.0f);
    float q = 0.f;
#pragma unroll
    for (int i = 0; i < 8; i++) { const float d = v[i] - mean; q += d * d; }
#pragma unroll
    for (int o = 1; o < 64; o <<= 1) q += __shfl_xor(q, o, 64);
    const float inv = rsqrtf(q * (1.0f / 512.0f) + 1e-5f);
    short8 ov;
#pragma unroll
    for (int i = 0; i < 8; i++)
        ov[i] = (short)f2b((v[i] - mean) * inv * getf(g, off + c0 + i, F)
                           + getf(bta, off + c0 + i, F));
    *(short8*)(xp + c0) = ov;
}

// ---------------------------------------------------------------------------
__global__ __launch_bounds__(256)
void embed_kernel(const void* __restrict__ loc, const void* __restrict__ tds,
                  const void* __restrict__ Wtd, const void* __restrict__ btd,
                  const void* __restrict__ Wemb, const void* __restrict__ bemb,
                  u16* __restrict__ x, const int* __restrict__ flagp,
                  const int* __restrict__ dlen)
{
    const int token = blockIdx.x;
    if ((token & 1023) >= dlen[token >> 10]) return;
    const int F = *flagp;
    const int tid = threadIdx.x;
    __shared__ float inv[19];
    if (tid < 16) {
        inv[tid] = getf(loc, (size_t)token * 16 + tid, F);
    } else if (tid < 19) {
        const int e = tid - 16;
        float a = getf(btd, e, F);
        for (int j = 0; j < 8; j++)
            a += getf(tds, (size_t)token * 8 + j, F) * getf(Wtd, j * 3 + e, F);
        inv[tid] = a;
    }
    __syncthreads();
    for (int d = tid; d < Dn; d += 256) {
        float a = getf(bemb, d, F);
#pragma unroll
        for (int i = 0; i < 19; i++) a += inv[i] * getf(Wemb, (size_t)i * Dn + d, F);
        x[(size_t)token * Dn + d] = f2b(a);
    }
}

// ---------------------------------------------------------------------------
__global__ __launch_bounds__(256)
void transpose_w(const void* __restrict__ src, u16* __restrict__ dst,
                 int K, int N, const int* __restrict__ flagp)
{
    const int F = *flagp;
    __shared__ u16 tile[32][33];
    const size_t ls = (size_t)K * N;
    const size_t sb = (size_t)blockIdx.z * ls;
    u16* d = dst + blockIdx.z * ls;
    const int tx = threadIdx.x & 31, ty = threadIdx.x >> 5;
    const int n0 = blockIdx.x * 32, k0 = blockIdx.y * 32;
#pragma unroll
    for (int i = 0; i < 32; i += 8)
        tile[ty + i][tx] = f2b(getf(src, sb + (size_t)(k0 + ty + i) * N + n0 + tx, F));
    __syncthreads();
#pragma unroll
    for (int i = 0; i < 32; i += 8)
        d[(size_t)(n0 + ty + i) * K + k0 + tx] = tile[tx][ty + i];
}

// ---------------------------------------------------------------------------
// Head: whole-block dead early-out, Wout in LDS stride 516, b64 reads.
// ---------------------------------------------------------------------------
__global__ __launch_bounds__(256)
void final_proj(const u16* __restrict__ x, const void* __restrict__ Wout,
                const void* __restrict__ Wcomb, const void* __restrict__ addr,
                const void* __restrict__ poi, const int* __restrict__ atype,
                const void* __restrict__ Wa, const void* __restrict__ ba,
                float* __restrict__ logits, const int* __restrict__ flagp,
                const int* __restrict__ dlen)
{
    const int t0 = blockIdx.x * 8;
    if ((t0 & 1023) >= dlen[t0 >> 10]) return;   // all 8 tokens dead
    const int F = *flagp;
    __shared__ float xs[8][512];
    __shared__ __align__(8) u16 wlds[32 * 516];
    const int tid = threadIdx.x;
    for (int i = tid; i < 8 * 512; i += 256) {
        const int tk = i >> 9, d = i & 511;
        xs[tk][d] = b2f(x[(size_t)(t0 + tk) * Dn + d]);
    }
    for (int i = tid; i < 16384; i += 256) {
        const int k = i >> 5, j = i & 31;
        wlds[j * 516 + k] = F ? f2b(((const float*)Wout)[(size_t)k * 32 + j])
                              : ((const u16*)Wout)[(size_t)k * 32 + j];
    }
    __syncthreads();
    const int half = tid >> 5, j = tid & 31;
    const int token = t0 + half;
    const int b = token >> 10;
    if ((token & 1023) >= dlen[b]) return;
    const int ty = atype[b];
    float a = getf(ba, j, F) + getf(addr, b, F) * getf(Wa, j, F);
#pragma unroll
    for (int e = 0; e < 3; e++)
        a += getf(poi, ty * 3 + e, F) * getf(Wa, (1 + e) * 32 + j, F);
    float s = a;
    const u16* wj = wlds + j * 516;
    const float* xr = xs[half];
#pragma unroll 4
    for (int k = 0; k < 512; k += 4) {
        const uint2 wv = *(const uint2*)&wj[k];
        s += xr[k]     * asf(wv.x << 16);
        s += xr[k + 1] * asf(wv.x & 0xFFFF0000u);
        s += xr[k + 2] * asf(wv.y << 16);
        s += xr[k + 3] * asf(wv.y & 0xFFFF0000u);
    }
    float o = tanhf(s) * getf(Wcomb, j, F);
#pragma unroll
    for (int off = 1; off < 32; off <<= 1) o += __shfl_xor(o, off, 64);
    if (j == 0) logits[token] = o;
}

// ---------------------------------------------------------------------------
__global__ __launch_bounds__(256)
void lsm_kernel(const float* __restrict__ logits, const int* __restrict__ dlen,
                float* __restrict__ out)
{
    const int b = blockIdx.x, tid = threadIdx.x;
    const int len = dlen[b];
    const float* lp = logits + (size_t)b * Sn;
    __shared__ float wA[4], wB[4];
    float mx = -3e38f;
    for (int s = tid; s < Sn; s += 256) if (s < len) mx = fmaxf(mx, lp[s]);
#pragma unroll
    for (int o = 1; o < 64; o <<= 1) mx = fmaxf(mx, __shfl_xor(mx, o, 64));
    if ((tid & 63) == 0) wA[tid >> 6] = mx;
    __syncthreads();
    mx = fmaxf(fmaxf(wA[0], wA[1]), fmaxf(wA[2], wA[3]));
    float sm = 0.f;
    for (int s = tid; s < Sn; s += 256) if (s < len) sm += __expf(lp[s] - mx);
#pragma unroll
    for (int o = 1; o < 64; o <<= 1) sm += __shfl_xor(sm, o, 64);
    if ((tid & 63) == 0) wB[tid >> 6] = sm;
    __syncthreads();
    const float lse = mx + __logf(wB[0] + wB[1] + wB[2] + wB[3]);
    for (int s = tid; s < Sn; s += 256)
        out[(size_t)b * Sn + s] = (s < len) ? (lp[s] - lse) : 0.0f;
}

// ---------------------------------------------------------------------------
extern "C" void kernel_launch(void* const* d_in, const int* in_sizes, int n_in,
                              void* d_out, int out_size, void* d_ws, size_t ws_size,
                              hipStream_t stream) {
    const void* addr  = d_in[0];
    const void* loc   = d_in[1];
    const void* tds   = d_in[2];
    const void* Wtd   = d_in[3];
    const void* btd   = d_in[4];
    const void* Wemb  = d_in[5];
    const void* bemb  = d_in[6];
    const void* Wqkv  = d_in[7];
    const void* bqkv  = d_in[8];
    const void* Wo    = d_in[9];
    const void* bo    = d_in[10];
    const void* ln1g  = d_in[11];
    const void* ln1b  = d_in[12];
    const void* W1    = d_in[13];
    const void* b1    = d_in[14];
    const void* W2    = d_in[15];
    const void* b2    = d_in[16];
    const void* ln2g  = d_in[17];
    const void* ln2b  = d_in[18];
    const void* poi   = d_in[19];
    const void* Wa    = d_in[20];
    const void* ba    = d_in[21];
    const void* Wout  = d_in[22];
    const void* Wcomb = d_in[23];
    const int* atype  = (const int*)d_in[24];
    const int* dlen   = (const int*)d_in[25];

    char* base = (char*)d_ws;
    u16*   xb    = (u16*)(base);                  // 33,554,432  x [B,S,D]
    u16*   qkvp  = (u16*)(base + 33554432ull);    // 100,663,296 packed q|k|v
    u16*   ctxb  = (u16*)(base + 134217728ull);   // 33,554,432  ctx / ff-hidden
    u16*   tb    = (u16*)(base + 167772160ull);   // 33,554,432  pre-LN GEMM out
    u16*   wqkvT = (u16*)(base + 201326592ull);   // 6,291,456
    u16*   woT   = (u16*)(base + 207618048ull);   // 2,097,152
    u16*   w1T   = (u16*)(base + 209715200ull);   // 2,097,152
    u16*   w2T   = (u16*)(base + 211812352ull);   // 2,097,152
    float* logit = (float*)(base + 213909504ull); // 131,072
    int*   flag  = (int*)  (base + 214040576ull); // 4
    if (ws_size < 214040592ull) return;

    detect_kernel<<<1, 256, 0, stream>>>(loc, flag);

    transpose_w<<<dim3(48, 16, 4), 256, 0, stream>>>(Wqkv, wqkvT, 512, 1536, flag);
    transpose_w<<<dim3(16, 16, 4), 256, 0, stream>>>(Wo,   woT,   512, 512, flag);
    transpose_w<<<dim3(16, 16, 4), 256, 0, stream>>>(W1,   w1T,   512, 512, flag);
    transpose_w<<<dim3(16, 16, 4), 256, 0, stream>>>(W2,   w2T,   512, 512, flag);

    embed_kernel<<<BS, 256, 0, stream>>>(loc, tds, Wtd, btd, Wemb, bemb, xb, flag, dlen);

    for (int l = 0; l < Ln; l++) {
        gemm_bt<<<dim3(12, 256), 256, 0, stream>>>(
            xb, wqkvT + (size_t)l * 1536 * 512, bqkv, l * 1536, qkvp, 1536, 512, 0, 1, flag, dlen);
        attn_kernel<<<2048, 256, 0, stream>>>(qkvp, dlen, ctxb);
        gemm_bt<<<dim3(4, 256), 256, 0, stream>>>(
            ctxb, woT + (size_t)l * 512 * 512, bo, l * 512, tb, 512, 512, 0, 0, flag, dlen);
        ln_res<<<BS / 4, 256, 0, stream>>>(xb, tb, ln1g, ln1b, l * 512, flag, dlen);
        gemm_bt<<<dim3(4, 256), 256, 0, stream>>>(
            xb, w1T + (size_t)l * 512 * 512, b1, l * 512, ctxb, 512, 512, 1, 0, flag, dlen);
        gemm_bt<<<dim3(4, 256), 256, 0, stream>>>(
            ctxb, w2T + (size_t)l * 512 * 512, b2, l * 512, tb, 512, 512, 0, 0, flag, dlen);
        ln_res<<<BS / 4, 256, 0, stream>>>(xb, tb, ln2g, ln2b, l * 512, flag, dlen);
    }

    final_proj<<<BS / 8, 256, 0, stream>>>(xb, Wout, Wcomb, addr, poi, atype,
                                           Wa, ba, logit, flag, dlen);
    lsm_kernel<<<Bn, 256, 0, stream>>>(logit, dlen, (float*)d_out);
}